// Round 1
// baseline (21494.766 us; speedup 1.0000x reference)
//
#include <hip/hip_runtime.h>
#include <math.h>

// Problem constants
#define TT 256
#define BB 32
#define VV 4712
#define HH 500
#define FOURH 2000
#define MPRE 8160          // 255*32
#define NBLK_REC 250

// ---------------- workspace layout (float offsets) ----------------
// logits   : 0            .. 38,449,920   (8160*4712)
//   enc_pre: 0            .. 16,320,000   (8160*2000)  overlaps logits
//   dec_pre: 16,320,000   .. 32,640,000                overlaps logits
// dec_h    : 38,449,920   .. 42,529,920   (8160*500)
// h_a      : 42,529,920   .. 42,545,920   (32*500)
// h_b      : 42,545,920   .. 42,561,920
// nll      : 42,561,920   .. 42,570,112   (8192)
// bar      : 42,570,112   (4 uints)

#define OFF_DECPRE 16320000
#define OFF_DECH   38449920
#define OFF_HA     42529920
#define OFF_HB     42545920
#define OFF_NLL    42561920
#define OFF_BAR    42570112

// ---------------- generic fp32 tiled GEMM: C[m][n] = sum_k A[row(m)][k]*W[n][k] + b0[n] + b1[n]
// 128x128 tile, BK=16, 256 threads, 8x8 per thread (two 4-wide halves 64 apart)
__global__ __launch_bounds__(256) void gemm128(
    const float* __restrict__ A, int lda, int rowmap,
    const float* __restrict__ W,
    const float* __restrict__ b0, const float* __restrict__ b1,
    float* __restrict__ C, int ldc, int M, int N, int K) {
  __shared__ __align__(16) float As[16][132];
  __shared__ __align__(16) float Ws[16][132];
  const int tid = threadIdx.x;
  const int tx = tid & 15, ty = tid >> 4;
  const int m0 = blockIdx.x * 128, n0 = blockIdx.y * 128;

  float acc[2][2][4][4];
#pragma unroll
  for (int a = 0; a < 2; ++a)
#pragma unroll
    for (int b = 0; b < 2; ++b)
#pragma unroll
      for (int i = 0; i < 4; ++i)
#pragma unroll
        for (int j = 0; j < 4; ++j) acc[a][b][i][j] = 0.0f;

  const int srow = tid >> 2, kq0 = tid & 3;
  long arow[2];
  long wrow[2];
#pragma unroll
  for (int h = 0; h < 2; ++h) {
    int m = m0 + srow + h * 64;
    if (m >= M) m = M - 1;
    int rm = m;
    if (rowmap == 1) { int t = m >> 5, b = m & 31; rm = ((255 - t) << 5) + b; }
    arow[h] = (long)rm * lda;
    int n = n0 + srow + h * 64;
    if (n >= N) n = N - 1;
    wrow[h] = (long)n * K;
  }

  const int KT = (K + 15) >> 4;
  for (int kt = 0; kt < KT; ++kt) {
    const int kbase = kt * 16 + kq0 * 4;
    const bool kok = (kbase < K);  // K is a multiple of 4 for all our calls
#pragma unroll
    for (int h = 0; h < 2; ++h) {
      float4 av = make_float4(0.f, 0.f, 0.f, 0.f);
      float4 wv = make_float4(0.f, 0.f, 0.f, 0.f);
      if (kok) {
        av = *(const float4*)&A[arow[h] + kbase];
        wv = *(const float4*)&W[wrow[h] + kbase];
      }
      const int ml = srow + h * 64;
      As[kq0 * 4 + 0][ml] = av.x; As[kq0 * 4 + 1][ml] = av.y;
      As[kq0 * 4 + 2][ml] = av.z; As[kq0 * 4 + 3][ml] = av.w;
      Ws[kq0 * 4 + 0][ml] = wv.x; Ws[kq0 * 4 + 1][ml] = wv.y;
      Ws[kq0 * 4 + 2][ml] = wv.z; Ws[kq0 * 4 + 3][ml] = wv.w;
    }
    __syncthreads();
#pragma unroll
    for (int k = 0; k < 16; ++k) {
      const float4 a0 = *(const float4*)&As[k][ty << 2];
      const float4 a1 = *(const float4*)&As[k][64 + (ty << 2)];
      const float4 w0 = *(const float4*)&Ws[k][tx << 2];
      const float4 w1 = *(const float4*)&Ws[k][64 + (tx << 2)];
      const float am[2][4] = {{a0.x, a0.y, a0.z, a0.w}, {a1.x, a1.y, a1.z, a1.w}};
      const float wn[2][4] = {{w0.x, w0.y, w0.z, w0.w}, {w1.x, w1.y, w1.z, w1.w}};
#pragma unroll
      for (int mh = 0; mh < 2; ++mh)
#pragma unroll
        for (int nh = 0; nh < 2; ++nh)
#pragma unroll
          for (int i = 0; i < 4; ++i)
#pragma unroll
            for (int j = 0; j < 4; ++j)
              acc[mh][nh][i][j] += am[mh][i] * wn[nh][j];
    }
    __syncthreads();
  }

  // epilogue
  float4 biasv[2];
#pragma unroll
  for (int nh = 0; nh < 2; ++nh) {
    const int n = n0 + nh * 64 + (tx << 2);
    biasv[nh] = make_float4(0.f, 0.f, 0.f, 0.f);
    if (n < N) {
      if (b0) {
        float4 v = *(const float4*)&b0[n];
        biasv[nh].x += v.x; biasv[nh].y += v.y; biasv[nh].z += v.z; biasv[nh].w += v.w;
      }
      if (b1) {
        float4 v = *(const float4*)&b1[n];
        biasv[nh].x += v.x; biasv[nh].y += v.y; biasv[nh].z += v.z; biasv[nh].w += v.w;
      }
    }
  }
#pragma unroll
  for (int mh = 0; mh < 2; ++mh)
#pragma unroll
    for (int i = 0; i < 4; ++i) {
      const int m = m0 + mh * 64 + (ty << 2) + i;
      if (m < M) {
        float* crow = C + (long)m * ldc;
#pragma unroll
        for (int nh = 0; nh < 2; ++nh) {
          const int n = n0 + nh * 64 + (tx << 2);
          if (n < N) {
            float4 o;
            o.x = acc[mh][nh][i][0] + biasv[nh].x;
            o.y = acc[mh][nh][i][1] + biasv[nh].y;
            o.z = acc[mh][nh][i][2] + biasv[nh].z;
            o.w = acc[mh][nh][i][3] + biasv[nh].w;
            *(float4*)&crow[n] = o;
          }
        }
      }
    }
}

// ---------------- grid barrier (device-scope, sense via generation counter) ----------------
__device__ __forceinline__ void gbar(unsigned* cnt, unsigned* gen) {
  __syncthreads();
  if (threadIdx.x == 0) {
    __threadfence();
    unsigned g = __hip_atomic_load(gen, __ATOMIC_RELAXED, __HIP_MEMORY_SCOPE_AGENT);
    unsigned old = __hip_atomic_fetch_add(cnt, 1u, __ATOMIC_ACQ_REL, __HIP_MEMORY_SCOPE_AGENT);
    if (old == NBLK_REC - 1) {
      __hip_atomic_store(cnt, 0u, __ATOMIC_RELAXED, __HIP_MEMORY_SCOPE_AGENT);
      __hip_atomic_fetch_add(gen, 1u, __ATOMIC_RELEASE, __HIP_MEMORY_SCOPE_AGENT);
    } else {
      while (__hip_atomic_load(gen, __ATOMIC_ACQUIRE, __HIP_MEMORY_SCOPE_AGENT) == g) {
        __builtin_amdgcn_s_sleep(4);
      }
    }
  }
  __syncthreads();
}

// ---------------- persistent LSTM recurrence (encoder 255 steps then decoder 255 steps)
// 250 blocks, each owns 2 hidden units (8 gate rows). h broadcast via global ping/pong.
// Per step: stage h into LDS [k][b] (two 256-k passes), 16-way k-split dot, LDS reduce,
// gate nonlinearity, write h slice (+dec_h), grid barrier.
__global__ __launch_bounds__(256) void lstm_rec(
    const float* __restrict__ enc_pre, const float* __restrict__ dec_pre,
    const float* __restrict__ enc_Whh, const float* __restrict__ dec_Whh,
    float* __restrict__ h_a, float* __restrict__ h_b,
    float* __restrict__ dec_h, unsigned* __restrict__ bar) {
  __shared__ __align__(16) float hs[256 * 32];   // [k_local][b]; front 4352 floats aliased by red/gex
  __shared__ __align__(16) float wsl[512 * 8];   // [k][r], zero-padded k>=500
  __shared__ float cbuf[64];                     // persistent cell state [ul*32+b]
  float* redb = hs;            // 16*16*16 partials
  float* gex = hs + 4096;      // 8*32 gate exchange

  const int tid = threadIdx.x;
  const int ks = tid >> 4;          // 0..15 k-split
  const int tm = (tid & 15) >> 1;   // 0..7  b-group (4 b each)
  const int tn = tid & 1;           // 0..1  row-group (4 rows each)
  const int u0 = blockIdx.x * 2;

  if (tid < 64) cbuf[tid] = 0.0f;

  const float* pres[2] = {enc_pre, dec_pre};
  const float* whhs[2] = {enc_Whh, dec_Whh};
  float* hcur = h_a;
  float* hnxt = h_b;

  for (int ph = 0; ph < 2; ++ph) {
    const float* pre = pres[ph];
    const float* Whh = whhs[ph];
    __syncthreads();
    // stage Whh slice: rows r = ul*4+gate -> global row gate*500 + u0 + ul
    for (int c = tid; c < 1024; c += 256) {
      const int r = c & 7, kq = c >> 3;
      const int k = kq << 2;
      float4 v = make_float4(0.f, 0.f, 0.f, 0.f);
      if (k < 500) {
        const int j = (r & 3) * 500 + u0 + (r >> 2);
        v = *(const float4*)&Whh[j * 500 + k];
      }
      wsl[(k + 0) * 8 + r] = v.x;
      wsl[(k + 1) * 8 + r] = v.y;
      wsl[(k + 2) * 8 + r] = v.z;
      wsl[(k + 3) * 8 + r] = v.w;
    }
    __syncthreads();

    for (int t = 0; t < 255; ++t) {
      float acc[4][4];
#pragma unroll
      for (int a = 0; a < 4; ++a)
#pragma unroll
        for (int b = 0; b < 4; ++b) acc[a][b] = 0.0f;

      for (int p = 0; p < 2; ++p) {
        // stage h chunk k in [p*256, p*256+256)
        for (int c = tid; c < 2048; c += 256) {
          const int b = c & 31, kq = c >> 5;
          const int k = (p << 8) + (kq << 2);
          float4 v = make_float4(0.f, 0.f, 0.f, 0.f);
          if (k < 500) v = *(const float4*)&hcur[b * 500 + k];
          const int kl = kq << 2;
          hs[(kl + 0) * 32 + b] = v.x;
          hs[(kl + 1) * 32 + b] = v.y;
          hs[(kl + 2) * 32 + b] = v.z;
          hs[(kl + 3) * 32 + b] = v.w;
        }
        __syncthreads();
#pragma unroll
        for (int jj = 0; jj < 16; ++jj) {
          const int kl = (jj << 4) + ks;
          const int k = (p << 8) + kl;
          const float4 h4 = *(const float4*)&hs[kl * 32 + (tm << 2)];
          const float4 w4 = *(const float4*)&wsl[k * 8 + (tn << 2)];
          acc[0][0] += w4.x * h4.x; acc[0][1] += w4.x * h4.y; acc[0][2] += w4.x * h4.z; acc[0][3] += w4.x * h4.w;
          acc[1][0] += w4.y * h4.x; acc[1][1] += w4.y * h4.y; acc[1][2] += w4.y * h4.z; acc[1][3] += w4.y * h4.w;
          acc[2][0] += w4.z * h4.x; acc[2][1] += w4.z * h4.y; acc[2][2] += w4.z * h4.z; acc[2][3] += w4.z * h4.w;
          acc[3][0] += w4.w * h4.x; acc[3][1] += w4.w * h4.y; acc[3][2] += w4.w * h4.z; acc[3][3] += w4.w * h4.w;
        }
        __syncthreads();   // hs readers done (also guards red alias after p==1)
      }

      // write k-split partials: acc[r][i] -> red[ks][pos][r*4+i]
      const int pos = (tm << 1) | tn;
#pragma unroll
      for (int r = 0; r < 4; ++r) {
        float4 v = make_float4(acc[r][0], acc[r][1], acc[r][2], acc[r][3]);
        *(float4*)&redb[((ks << 4) + pos) * 16 + (r << 2)] = v;
      }
      __syncthreads();
      // reduce: thread d -> dot (row, b)
      {
        const int pos2 = tid >> 4, v2 = tid & 15;
        const int row = ((pos2 & 1) << 2) + (v2 >> 2);
        const int b = ((pos2 >> 1) << 2) + (v2 & 3);
        float g = 0.0f;
#pragma unroll
        for (int kk = 0; kk < 16; ++kk) g += redb[((kk << 4) + pos2) * 16 + v2];
        const int jglob = (row & 3) * 500 + u0 + (row >> 2);
        g += pre[(t * 32 + b) * 2000 + jglob];
        gex[row * 32 + b] = g;
      }
      __syncthreads();
      if (tid < 64) {
        const int ul = tid >> 5, b = tid & 31;
        const float iv = gex[(ul * 4 + 0) * 32 + b];
        const float fv = gex[(ul * 4 + 1) * 32 + b];
        const float gv = gex[(ul * 4 + 2) * 32 + b];
        const float ov = gex[(ul * 4 + 3) * 32 + b];
        const float co = cbuf[(ul << 5) + b];
        const float si = 1.0f / (1.0f + expf(-iv));
        const float sf = 1.0f / (1.0f + expf(-fv));
        const float so = 1.0f / (1.0f + expf(-ov));
        const float cn = sf * co + si * tanhf(gv);
        const float hn = so * tanhf(cn);
        cbuf[(ul << 5) + b] = cn;
        const int u = u0 + ul;
        hnxt[b * 500 + u] = hn;
        if (ph == 1) dec_h[(t * 32 + b) * 500 + u] = hn;
      }
      gbar(bar, bar + 1);
      float* tmpp = hcur; hcur = hnxt; hnxt = tmpp;
    }
  }
}

// ---------------- per-row log-softmax NLL ----------------
__device__ __forceinline__ float wave_max(float v) {
#pragma unroll
  for (int o = 32; o > 0; o >>= 1) v = fmaxf(v, __shfl_xor(v, o, 64));
  return v;
}
__device__ __forceinline__ float wave_sum(float v) {
#pragma unroll
  for (int o = 32; o > 0; o >>= 1) v += __shfl_xor(v, o, 64);
  return v;
}

__global__ __launch_bounds__(256) void loss_rows(
    const float* __restrict__ seq, const float* __restrict__ logits,
    const int* __restrict__ nseq, float* __restrict__ nll) {
  __shared__ float sm[8];
  const int r = blockIdx.x, tid = threadIdx.x;
  const int t = r >> 5, b = r & 31;
  const float* row = (t == 0) ? (seq + (long)b * VV)
                              : (logits + (long)((t - 1) * 32 + b) * VV);
  float m = -INFINITY;
  for (int c = tid; c < 1178; c += 256) {  // 1178*4 = 4712 exactly
    float4 v = *(const float4*)&row[c * 4];
    m = fmaxf(m, fmaxf(fmaxf(v.x, v.y), fmaxf(v.z, v.w)));
  }
  m = wave_max(m);
  const int wid = tid >> 6;
  if ((tid & 63) == 0) sm[wid] = m;
  __syncthreads();
  const float M4 = fmaxf(fmaxf(sm[0], sm[1]), fmaxf(sm[2], sm[3]));
  float s = 0.0f;
  for (int c = tid; c < 1178; c += 256) {
    float4 v = *(const float4*)&row[c * 4];
    s += expf(v.x - M4) + expf(v.y - M4) + expf(v.z - M4) + expf(v.w - M4);
  }
  s = wave_sum(s);
  if ((tid & 63) == 0) sm[4 + wid] = s;
  __syncthreads();
  if (tid == 0) {
    const float S = sm[4] + sm[5] + sm[6] + sm[7];
    const int tgt = nseq[(t << 5) + b];
    nll[r] = M4 + logf(S) - row[tgt];
  }
}

__global__ __launch_bounds__(256) void final_reduce(
    const float* __restrict__ nll, float* __restrict__ out) {
  __shared__ float sm[4];
  float s = 0.0f;
  for (int c = threadIdx.x; c < 8192; c += 256) s += nll[c];
  s = wave_sum(s);
  if ((threadIdx.x & 63) == 0) sm[threadIdx.x >> 6] = s;
  __syncthreads();
  if (threadIdx.x == 0) out[0] = (sm[0] + sm[1] + sm[2] + sm[3]) * (1.0f / 8192.0f);
}

// ---------------- launch ----------------
extern "C" void kernel_launch(void* const* d_in, const int* in_sizes, int n_in,
                              void* d_out, int out_size, void* d_ws, size_t ws_size,
                              hipStream_t stream) {
  (void)in_sizes; (void)n_in; (void)out_size; (void)ws_size;
  const float* seq  = (const float*)d_in[0];
  const int* nseq   = (const int*)d_in[1];
  const float* eWih = (const float*)d_in[2];
  const float* eWhh = (const float*)d_in[3];
  const float* ebih = (const float*)d_in[4];
  const float* ebhh = (const float*)d_in[5];
  const float* dWih = (const float*)d_in[6];
  const float* dWhh = (const float*)d_in[7];
  const float* dbih = (const float*)d_in[8];
  const float* dbhh = (const float*)d_in[9];
  const float* oW   = (const float*)d_in[10];
  const float* ob   = (const float*)d_in[11];

  float* wsf = (float*)d_ws;
  float* logits  = wsf;
  float* enc_pre = wsf;
  float* dec_pre = wsf + OFF_DECPRE;
  float* dec_h   = wsf + OFF_DECH;
  float* h_a     = wsf + OFF_HA;
  float* h_b     = wsf + OFF_HB;
  float* nll     = wsf + OFF_NLL;
  unsigned* bar  = (unsigned*)(wsf + OFF_BAR);

  hipMemsetAsync(h_a, 0, 16000 * sizeof(float), stream);
  hipMemsetAsync(bar, 0, 4 * sizeof(unsigned), stream);

  dim3 blk(256);
  // enc_pre = reversed(seq) @ enc_Wih^T + (ebih + ebhh)
  gemm128<<<dim3(64, 16), blk, 0, stream>>>(seq, VV, 1, eWih, ebih, ebhh,
                                            enc_pre, FOURH, MPRE, FOURH, VV);
  // dec_pre = seq[:-1] @ dec_Wih^T + (dbih + dbhh)
  gemm128<<<dim3(64, 16), blk, 0, stream>>>(seq, VV, 0, dWih, dbih, dbhh,
                                            dec_pre, FOURH, MPRE, FOURH, VV);
  // recurrence (encoder then decoder), writes dec_h
  lstm_rec<<<dim3(NBLK_REC), blk, 0, stream>>>(enc_pre, dec_pre, eWhh, dWhh,
                                               h_a, h_b, dec_h, bar);
  // logits = dec_h @ out_W^T + out_b   (overwrites pre buffers; dec_h disjoint)
  gemm128<<<dim3(64, 37), blk, 0, stream>>>(dec_h, HH, 0, oW, ob, nullptr,
                                            logits, VV, MPRE, VV, HH);
  // per-row NLL then deterministic reduce
  loss_rows<<<dim3(8192), blk, 0, stream>>>(seq, logits, nseq, nll);
  final_reduce<<<dim3(1), blk, 0, stream>>>(nll, (float*)d_out);
}